// Round 6
// baseline (278.135 us; speedup 1.0000x reference)
//
#include <hip/hip_runtime.h>
#include <math.h>

#define NH 12
#define DMODEL 768
#define DHEAD 64
#define BATCH 16
#define SEQ 512
#define NTOK (BATCH*SEQ)   // 8192
#define ATTN_SCALE 0.125f
#define LN_EPS 1e-3f
#define PADP 72            // padded LDS row length (shorts) for the P tile
#define NKT 12             // K tiles of 64 (K = 768)

typedef __attribute__((ext_vector_type(8))) short  bf16x8;
typedef __attribute__((ext_vector_type(4))) float  f32x4;

__device__ __forceinline__ unsigned short f2bf(float f) {
    unsigned int u = __float_as_uint(f);
    unsigned int r = (u + 0x7fffu + ((u >> 16) & 1u)) >> 16;
    return (unsigned short)r;
}

__device__ __forceinline__ void async_copy16(const void* g, void* l) {
    __builtin_amdgcn_global_load_lds((const __attribute__((address_space(1))) void*)g,
                                     (__attribute__((address_space(3))) void*)l,
                                     16, 0, 0);
}

#define SBAR() do { \
    __builtin_amdgcn_sched_barrier(0); \
    __builtin_amdgcn_s_barrier(); \
    __builtin_amdgcn_sched_barrier(0); \
} while (0)

#define VMW0() do { \
    __builtin_amdgcn_sched_barrier(0); \
    asm volatile("s_waitcnt vmcnt(0)" ::: "memory"); \
    __builtin_amdgcn_sched_barrier(0); \
} while (0)

// ---------------------------------------------------------------------------
// Merged prep: blocks [0,6144) cast x fp32->bf16; blocks [6144,8448) build
// Wt[n][k] = bf16(W[k][n]) for the 4 weight matrices. (wtq/wtk/wtv are
// CONTIGUOUS in the workspace -> merged [2304][768] B matrix.)
// ---------------------------------------------------------------------------
__global__ __launch_bounds__(256) void prep_kernel(
    const float* __restrict__ x,
    const float* __restrict__ Wq, const float* __restrict__ Wk,
    const float* __restrict__ Wv, const float* __restrict__ Wo,
    unsigned short* __restrict__ xb,
    unsigned short* __restrict__ tq, unsigned short* __restrict__ tk,
    unsigned short* __restrict__ tv, unsigned short* __restrict__ to_)
{
    __shared__ float tile[32][33];
    const int bid = blockIdx.x;
    const int tid = threadIdx.x;

    if (bid < 6144) {
        int i = (bid * 256 + tid) * 4;
        const float4 v = *(const float4*)(x + i);
        unsigned long long pack =
              (unsigned long long)f2bf(v.x)
            | ((unsigned long long)f2bf(v.y) << 16)
            | ((unsigned long long)f2bf(v.z) << 32)
            | ((unsigned long long)f2bf(v.w) << 48);
        *(unsigned long long*)(xb + i) = pack;
        return;
    }

    const int t   = bid - 6144;       // 0..2303
    const int zz  = t / 576;
    const int rem = t % 576;
    const float* W = (zz == 0) ? Wq : (zz == 1) ? Wk : (zz == 2) ? Wv : Wo;
    unsigned short* T = (zz == 0) ? tq : (zz == 1) ? tk : (zz == 2) ? tv : to_;

    const int bx = (rem / 24) * 32;   // k base
    const int by = (rem % 24) * 32;   // n base
    const int tx = tid & 31, ty = tid >> 5;   // ty 0..7

    #pragma unroll
    for (int i = 0; i < 32; i += 8)
        tile[ty + i][tx] = W[(size_t)(bx + ty + i) * DMODEL + by + tx];
    __syncthreads();
    #pragma unroll
    for (int i = 0; i < 32; i += 8)
        T[(size_t)(by + ty + i) * DMODEL + bx + tx] = f2bf(tile[tx][ty + i]);
}

// ---------------------------------------------------------------------------
// qkv GEMM (UNCHANGED from R5, best measured 45.0us): BM=256 x BN=288, BK=64,
// double-buffered, 256 blocks = 1/CU, XOR chunk swizzle (0 conflicts), one
// barrier + one vmcnt(0) per K-tile.
// ---------------------------------------------------------------------------
#define QSTAGE(kt, sb) do { \
    const int _k0 = (kt) * 64; \
    _Pragma("unroll") \
    for (int _i = 0; _i < 4; ++_i) \
        async_copy16(aSrc + (size_t)_i * (8 * DMODEL) + _k0, &As[sb][(w * 4 + _i) * 512]); \
    _Pragma("unroll") \
    for (int _i = 0; _i < 4; ++_i) \
        async_copy16(bSrc + (size_t)_i * (64 * DMODEL) + _k0, &Bs[sb][(w + 8 * _i) * 512]); \
    if (w < 4) \
        async_copy16(bSrc + (size_t)4 * (64 * DMODEL) + _k0, &Bs[sb][(w + 32) * 512]); \
} while (0)

#define QTILE(t, c, o, hasNext) do { \
    if (hasNext) QSTAGE((t) + 1, o); \
    bf16x8 aF[4][2]; \
    _Pragma("unroll") \
    for (int _m = 0; _m < 4; ++_m) { \
        const int _row = wm * 64 + _m * 16 + l16; \
        aF[_m][0] = *(const bf16x8*)&As[c][_row * 64 + p0]; \
        aF[_m][1] = *(const bf16x8*)&As[c][_row * 64 + (p0 ^ 32)]; \
    } \
    _Pragma("unroll") \
    for (int _nh = 0; _nh < 3; ++_nh) { \
        bf16x8 bF[3][2]; \
        _Pragma("unroll") \
        for (int _n = 0; _n < 3; ++_n) { \
            const int _row = wn * 144 + (_nh * 3 + _n) * 16 + l16; \
            bF[_n][0] = *(const bf16x8*)&Bs[c][_row * 64 + p0]; \
            bF[_n][1] = *(const bf16x8*)&Bs[c][_row * 64 + (p0 ^ 32)]; \
        } \
        __builtin_amdgcn_s_setprio(1); \
        _Pragma("unroll") \
        for (int _k = 0; _k < 2; ++_k) \
          _Pragma("unroll") \
          for (int _m = 0; _m < 4; ++_m) \
            _Pragma("unroll") \
            for (int _n = 0; _n < 3; ++_n) \
              acc[_m][_nh * 3 + _n] = __builtin_amdgcn_mfma_f32_16x16x32_bf16( \
                  aF[_m][_k], bF[_n][_k], acc[_m][_nh * 3 + _n], 0, 0, 0); \
        __builtin_amdgcn_s_setprio(0); \
    } \
    if (hasNext) VMW0(); \
    SBAR(); \
} while (0)

__global__ __launch_bounds__(512, 2) void gemm_db_qkv(
    const unsigned short* __restrict__ xb, const unsigned short* __restrict__ wt,
    const float* __restrict__ bq, const float* __restrict__ bk, const float* __restrict__ bv,
    unsigned short* __restrict__ o0, unsigned short* __restrict__ o1,
    unsigned short* __restrict__ o2)
{
    __shared__ __align__(16) unsigned short As[2][256 * 64];
    __shared__ __align__(16) unsigned short Bs[2][288 * 64];

    // bijective XCD swizzle: 256 blocks = 8 XCDs x 32 contiguous tiles
    const int orig = blockIdx.x;
    const int wg   = (orig & 7) * 32 + (orig >> 3);
    const int m0   = (wg >> 3) * 256;     // 32 M-tiles
    const int n0   = (wg & 7) * 288;      // 8 N-tiles

    const int tid  = threadIdx.x;
    const int lane = tid & 63;
    const int w    = tid >> 6;            // 0..7
    const int wm   = w >> 1, wn = w & 1;  // 4M x 2N wave grid
    const int quad = lane >> 4;
    const int l16  = lane & 15;
    const int rloc = lane >> 3;           // staging: row-within-inst 0..7
    const int csw  = (lane & 7) ^ rloc;   // swizzled logical chunk
    const int p0   = (quad ^ (l16 & 7)) * 8;

    const unsigned short* aSrc = xb + (size_t)(m0 + w * 32 + rloc) * DMODEL + csw * 8;
    const unsigned short* bSrc = wt + (size_t)(n0 + w * 8  + rloc) * DMODEL + csw * 8;

    f32x4 acc[4][9] = {};

    QSTAGE(0, 0);
    VMW0();
    SBAR();

    #pragma unroll 1
    for (int tt = 0; tt < NKT / 2; ++tt) {
        QTILE(2 * tt,     0, 1, 1);
        QTILE(2 * tt + 1, 1, 0, (tt < NKT / 2 - 1));
    }

    // epilogue: per 16-col group, pick q/k/v (wave-uniform: 16 | 768)
    #pragma unroll
    for (int nf = 0; nf < 9; ++nf) {
        const int ncg = n0 + wn * 144 + nf * 16 + l16;
        const int zz  = (ncg >= 1536) ? 2 : (ncg >= 768) ? 1 : 0;
        const int ncl = ncg - zz * 768;
        const int h = ncl >> 6, dh = ncl & 63;
        const float bval = ((zz == 0) ? bq : (zz == 1) ? bk : bv)[ncl];
        if (zz == 2) {
            // V^T layout: [B,H,DH,SEQ], pack 4 consecutive tokens per store
            #pragma unroll
            for (int mi = 0; mi < 4; ++mi) {
                const int mbase = m0 + wm * 64 + mi * 16 + quad * 4;
                const int bi = mbase >> 9, l = mbase & 511;
                unsigned long long pack = 0;
                #pragma unroll
                for (int r = 0; r < 4; ++r)
                    pack |= (unsigned long long)f2bf(acc[mi][nf][r] + bval) << (16 * r);
                *(unsigned long long*)(o2 + ((size_t)((bi * NH + h) * DHEAD + dh)) * SEQ + l) = pack;
            }
        } else {
            // Q/K layout: [B,H,SEQ,DH]; q pre-scaled by ATTN_SCALE
            const float sc = (zz == 0) ? ATTN_SCALE : 1.0f;
            unsigned short* out = (zz == 0) ? o0 : o1;
            #pragma unroll
            for (int mi = 0; mi < 4; ++mi) {
                const int mbase = m0 + wm * 64 + mi * 16 + quad * 4;
                #pragma unroll
                for (int r = 0; r < 4; ++r) {
                    const int t = mbase + r;
                    const int bi = t >> 9, l = t & 511;
                    out[(size_t)((bi * NH + h) * SEQ + l) * DHEAD + dh] =
                        f2bf((acc[mi][nf][r] + bval) * sc);
                }
            }
        }
    }
}

// ---------------------------------------------------------------------------
// O-proj (UNCHANGED from R5): BM=128 x BN=192, 256 blocks = 1/CU, one barrier
// + one vmcnt per tile. Epilogue: y = acc + bo + x.
// ---------------------------------------------------------------------------
#define OSTAGE(kt, sb) do { \
    const int _k0 = (kt) * 64; \
    _Pragma("unroll") \
    for (int _i = 0; _i < 2; ++_i) \
        async_copy16(aSrc + (size_t)_i * (8 * DMODEL) + _k0, &Ao[sb][(w * 2 + _i) * 512]); \
    _Pragma("unroll") \
    for (int _i = 0; _i < 3; ++_i) \
        async_copy16(bSrc + (size_t)_i * (8 * DMODEL) + _k0, &Bo[sb][(w * 3 + _i) * 512]); \
} while (0)

#define OTILE(t, c, o, hasNext) do { \
    if (hasNext) OSTAGE((t) + 1, o); \
    bf16x8 aF[4][2], bF[3][2]; \
    _Pragma("unroll") \
    for (int _m = 0; _m < 4; ++_m) { \
        const int _row = wm * 64 + _m * 16 + l16; \
        aF[_m][0] = *(const bf16x8*)&Ao[c][_row * 64 + p0]; \
        aF[_m][1] = *(const bf16x8*)&Ao[c][_row * 64 + (p0 ^ 32)]; \
    } \
    _Pragma("unroll") \
    for (int _n = 0; _n < 3; ++_n) { \
        const int _row = wn * 48 + _n * 16 + l16; \
        bF[_n][0] = *(const bf16x8*)&Bo[c][_row * 64 + p0]; \
        bF[_n][1] = *(const bf16x8*)&Bo[c][_row * 64 + (p0 ^ 32)]; \
    } \
    __builtin_amdgcn_s_setprio(1); \
    _Pragma("unroll") \
    for (int _k = 0; _k < 2; ++_k) \
      _Pragma("unroll") \
      for (int _m = 0; _m < 4; ++_m) \
        _Pragma("unroll") \
        for (int _n = 0; _n < 3; ++_n) \
          acc[_m][_n] = __builtin_amdgcn_mfma_f32_16x16x32_bf16( \
              aF[_m][_k], bF[_n][_k], acc[_m][_n], 0, 0, 0); \
    __builtin_amdgcn_s_setprio(0); \
    if (hasNext) VMW0(); \
    SBAR(); \
} while (0)

__global__ __launch_bounds__(512, 2) void gemm_db_oproj(
    const unsigned short* __restrict__ ctxb, const unsigned short* __restrict__ wto,
    const float* __restrict__ bo, const float* __restrict__ x,
    float* __restrict__ y)
{
    __shared__ __align__(16) unsigned short Ao[2][132 * 64];   // 128 rows + pad
    __shared__ __align__(16) unsigned short Bo[2][192 * 64];

    const int orig = blockIdx.x;
    const int wg   = (orig & 7) * 32 + (orig >> 3);   // 256 = 8 XCDs x 32
    const int m0   = (wg >> 2) * 128;                 // 64 M-tiles
    const int n0   = (wg & 3) * 192;                  // 4 N-tiles

    const int tid  = threadIdx.x;
    const int lane = tid & 63;
    const int w    = tid >> 6;            // 0..7
    const int wm   = w >> 2, wn = w & 3;  // 2M x 4N wave grid
    const int quad = lane >> 4;
    const int l16  = lane & 15;
    const int rloc = lane >> 3;
    const int csw  = (lane & 7) ^ rloc;
    const int p0   = (quad ^ (l16 & 7)) * 8;

    const unsigned short* aSrc = ctxb + (size_t)(m0 + w * 16 + rloc) * DMODEL + csw * 8;
    const unsigned short* bSrc = wto  + (size_t)(n0 + w * 24 + rloc) * DMODEL + csw * 8;

    f32x4 acc[4][3] = {};

    OSTAGE(0, 0);
    VMW0();
    SBAR();

    #pragma unroll 1
    for (int tt = 0; tt < NKT / 2; ++tt) {
        OTILE(2 * tt,     0, 1, 1);
        OTILE(2 * tt + 1, 1, 0, (tt < NKT / 2 - 1));
    }

    #pragma unroll
    for (int ni = 0; ni < 3; ++ni) {
        const int ncol = n0 + wn * 48 + ni * 16 + l16;
        const float bv_ = bo[ncol];
        #pragma unroll
        for (int mi = 0; mi < 4; ++mi) {
            const int mbase = m0 + wm * 64 + mi * 16 + quad * 4;
            #pragma unroll
            for (int r = 0; r < 4; ++r) {
                const size_t idx = (size_t)(mbase + r) * DMODEL + ncol;
                y[idx] = acc[mi][ni][r] + bv_ + x[idx];
            }
        }
    }
}

// ---------------------------------------------------------------------------
// MFMA flash attention v5: BARRIER-FREE, direct-from-L2 K/V.
// R5's version staged K/V in LDS (dbuf) + 8 __syncthreads/block; but K/V are
// L2/L3-resident (37.7 MB total, 8x q-tile reuse) -> staging was overhead
// (guide m169: dropping V-staging at L2-fit sizes was +26%). Now Q/K/V MFMA
// fragments load straight from global (de-swizzled addressing: lane(l16,quad)
// holds d = ks*32 + quad*8, verified against the working LDS layout); mask
// ints load directly per-iter and are always added (exp(s+0) bit-identical
// for the all-ones bench mask; masked case: exp(-1e9)=0 as before).
// Only LDS left: the wave-private Ps transpose buffer (no barrier needed --
// compiler orders the round-trip via lgkmcnt). ZERO barriers in the kernel;
// LDS 51 KB -> 9.2 KB so occupancy is VGPR-bound; unroll 2 for cross-iter
// load/compute overlap.
// ---------------------------------------------------------------------------
__global__ __launch_bounds__(256) void attn_mfma_kernel(
    const unsigned short* __restrict__ q, const unsigned short* __restrict__ k,
    const unsigned short* __restrict__ vt, const int* __restrict__ mask,
    unsigned short* __restrict__ ctxb)
{
    __shared__ __align__(16) unsigned short Ps[64 * PADP];

    const int tid  = threadIdx.x;
    const int lane = tid & 63;
    const int w    = tid >> 6;
    const int quad = lane >> 4;
    const int l16  = lane & 15;

    const int id = blockIdx.x;
    const int qt = id / (BATCH * NH);
    const int g  = id % (BATCH * NH);
    const int b  = g / NH, h = g % NH;
    const int q0 = qt * 64;

    const unsigned short* qp  = q  + ((size_t)(b * NH + h) * SEQ + q0) * DHEAD;
    const unsigned short* kp  = k  + (size_t)(b * NH + h) * SEQ * DHEAD;
    const unsigned short* vtp = vt + (size_t)(b * NH + h) * DHEAD * SEQ;
    const int* mrow = mask + b * SEQ;

    // Q fragment direct from global: row = w*16+l16, d = ks*32 + quad*8
    bf16x8 aQ[2];
    #pragma unroll
    for (int ks = 0; ks < 2; ++ks)
        aQ[ks] = *(const bf16x8*)(qp + (size_t)(w * 16 + l16) * DHEAD + ks * 32 + quad * 8);

    bf16x8 ones;
    #pragma unroll
    for (int j = 0; j < 8; ++j) ones[j] = (short)0x3F80;   // bf16 1.0

    f32x4 o[4] = {};
    f32x4 lsum = {0.f, 0.f, 0.f, 0.f};
    const f32x4 zf = {0.f, 0.f, 0.f, 0.f};

    #pragma unroll 2
    for (int it = 0; it < 8; ++it) {
        const int kt = it * 64;

        // S = (Q*scale)·K^T ; K frags direct: row = key, d = ks*32 + quad*8
        f32x4 s[4];
        #pragma unroll
        for (int ni = 0; ni < 4; ++ni) {
            const unsigned short* kr = kp + (size_t)(kt + ni * 16 + l16) * DHEAD + quad * 8;
            bf16x8 bK0 = *(const bf16x8*)(kr);
            bf16x8 bK1 = *(const bf16x8*)(kr + 32);
            f32x4 t0 = __builtin_amdgcn_mfma_f32_16x16x32_bf16(aQ[0], bK0, zf, 0, 0, 0);
            s[ni] = __builtin_amdgcn_mfma_f32_16x16x32_bf16(aQ[1], bK1, t0, 0, 0, 0);
        }

        // P = exp(S + mask) -> wave-private Ps (truncating bf16 cast)
        #pragma unroll
        for (int ni = 0; ni < 4; ++ni) {
            const float mk = (mrow[kt + ni * 16 + l16] > 0) ? 0.f : -1e9f;
            #pragma unroll
            for (int r = 0; r < 4; ++r)
                Ps[(w * 16 + quad * 4 + r) * PADP + ni * 16 + l16]
                    = (unsigned short)(__float_as_uint(__expf(s[ni][r] + mk)) >> 16);
        }

        // P back as A-frags (wave-internal LDS round trip; no barrier)
        bf16x8 aP[2];
        #pragma unroll
        for (int ks = 0; ks < 2; ++ks)
            aP[ks] = *(const bf16x8*)&Ps[(w * 16 + l16) * PADP + quad * 8 + ks * 32];

        // l += rowsum(P)
        lsum = __builtin_amdgcn_mfma_f32_16x16x32_bf16(aP[0], ones, lsum, 0, 0, 0);
        lsum = __builtin_amdgcn_mfma_f32_16x16x32_bf16(aP[1], ones, lsum, 0, 0, 0);

        // O += P · V ; V^T frags direct: row = d, key = kt + ks*32 + quad*8
        #pragma unroll
        for (int ni = 0; ni < 4; ++ni) {
            const unsigned short* vr = vtp + (size_t)(ni * 16 + l16) * SEQ + kt + quad * 8;
            bf16x8 bV0 = *(const bf16x8*)(vr);
            bf16x8 bV1 = *(const bf16x8*)(vr + 32);
            o[ni] = __builtin_amdgcn_mfma_f32_16x16x32_bf16(aP[0], bV0, o[ni], 0, 0, 0);
            o[ni] = __builtin_amdgcn_mfma_f32_16x16x32_bf16(aP[1], bV1, o[ni], 0, 0, 0);
        }
    }

    // epilogue: ctx[b, tok, h*64 + d] = O / l
    #pragma unroll
    for (int r = 0; r < 4; ++r) {
        const float inv = 1.f / lsum[r];
        const int tok = q0 + w * 16 + quad * 4 + r;
        #pragma unroll
        for (int ni = 0; ni < 4; ++ni)
            ctxb[(size_t)(b * SEQ + tok) * DMODEL + h * DHEAD + ni * 16 + l16]
                = f2bf(o[ni][r] * inv);
    }
}

// ---------------------------------------------------------------------------
// LayerNorm, in-place capable.
// ---------------------------------------------------------------------------
__global__ __launch_bounds__(256) void ln_kernel(
    const float* __restrict__ y, const float* __restrict__ gamma,
    const float* __restrict__ beta, float* __restrict__ out)
{
    const int t   = blockIdx.x;
    const int tid = threadIdx.x;
    const float* row = y + (size_t)t * DMODEL;

    float vals[3];
    float s = 0.f, s2 = 0.f;
    #pragma unroll
    for (int i = 0; i < 3; ++i) {
        float vv = row[tid + 256 * i];
        vals[i] = vv;
        s  += vv;
        s2 += vv * vv;
    }
    #pragma unroll
    for (int off = 32; off > 0; off >>= 1) {
        s  += __shfl_down(s,  off);
        s2 += __shfl_down(s2, off);
    }
    __shared__ float rbuf[8];
    int w = tid >> 6;
    if ((tid & 63) == 0) { rbuf[w] = s; rbuf[4 + w] = s2; }
    __syncthreads();
    float ts  = rbuf[0] + rbuf[1] + rbuf[2] + rbuf[3];
    float ts2 = rbuf[4] + rbuf[5] + rbuf[6] + rbuf[7];
    float mu  = ts * (1.f / DMODEL);
    float var = ts2 * (1.f / DMODEL) - mu * mu;
    float inv = rsqrtf(var + LN_EPS);
    #pragma unroll
    for (int i = 0; i < 3; ++i) {
        int c = tid + 256 * i;
        out[(size_t)t * DMODEL + c] = gamma[c] * (vals[i] - mu) * inv + beta[c];
    }
}

// ---------------------------------------------------------------------------
extern "C" void kernel_launch(void* const* d_in, const int* in_sizes, int n_in,
                              void* d_out, int out_size, void* d_ws, size_t ws_size,
                              hipStream_t stream) {
    const float* x     = (const float*)d_in[0];
    const int*   mask  = (const int*)  d_in[1];
    const float* Wq    = (const float*)d_in[2];
    const float* bq    = (const float*)d_in[3];
    const float* Wk    = (const float*)d_in[4];
    const float* bk    = (const float*)d_in[5];
    const float* Wv    = (const float*)d_in[6];
    const float* bv    = (const float*)d_in[7];
    const float* Wo    = (const float*)d_in[8];
    const float* bo    = (const float*)d_in[9];
    const float* gamma = (const float*)d_in[10];
    const float* beta  = (const float*)d_in[11];
    float* out = (float*)d_out;

    const size_t perTok = (size_t)NTOK * DMODEL;   // 6,291,456
    const size_t perW   = (size_t)DMODEL * DMODEL; //   589,824

    unsigned short* xb   = (unsigned short*)d_ws;
    unsigned short* wtq  = xb + perTok;            // wtq/wtk/wtv contiguous:
    unsigned short* wtk  = wtq + perW;             //   merged B = [2304][768]
    unsigned short* wtv  = wtk + perW;
    unsigned short* wto  = wtv + perW;
    unsigned short* qb   = wto + perW;
    unsigned short* kb   = qb + perTok;
    unsigned short* vb   = kb + perTok;            // holds V^T: [B,H,DH,SEQ]
    unsigned short* ctxb = vb + perTok;
    float* y = out;   // O-proj output lives in d_out; LN runs in-place

    prep_kernel<<<6144 + 2304, 256, 0, stream>>>(
        x, Wq, Wk, Wv, Wo, xb, wtq, wtk, wtv, wto);

    // merged QKV GEMM: [8192 x 768] x [768 x 2304], 256 blocks = 1/CU exact
    gemm_db_qkv<<<256, 512, 0, stream>>>(xb, wtq, bq, bk, bv, qb, kb, vb);

    attn_mfma_kernel<<<dim3((SEQ / 64) * BATCH * NH), 256, 0, stream>>>(
        qb, kb, vb, mask, ctxb);

    // O-proj: [8192 x 768] x [768 x 768], 256 blocks = 1/CU exact
    gemm_db_oproj<<<256, 512, 0, stream>>>(ctxb, wto, bo, x, y);

    ln_kernel<<<NTOK, 256, 0, stream>>>(y, gamma, beta, out);
}

// Round 7
// 188.182 us; speedup vs baseline: 1.4780x; 1.4780x over previous
//
#include <hip/hip_runtime.h>
#include <math.h>

#define NH 12
#define DMODEL 768
#define DHEAD 64
#define BATCH 16
#define SEQ 512
#define NTOK (BATCH*SEQ)   // 8192
#define ATTN_SCALE 0.125f
#define LN_EPS 1e-3f
#define PADP 72            // padded LDS row length (shorts) for the P tile
#define NKT 12             // K tiles of 64 (K = 768)

typedef __attribute__((ext_vector_type(8))) short  bf16x8;
typedef __attribute__((ext_vector_type(4))) float  f32x4;

__device__ __forceinline__ unsigned short f2bf(float f) {
    unsigned int u = __float_as_uint(f);
    unsigned int r = (u + 0x7fffu + ((u >> 16) & 1u)) >> 16;
    return (unsigned short)r;
}

__device__ __forceinline__ void async_copy16(const void* g, void* l) {
    __builtin_amdgcn_global_load_lds((const __attribute__((address_space(1))) void*)g,
                                     (__attribute__((address_space(3))) void*)l,
                                     16, 0, 0);
}

#define SBAR() do { \
    __builtin_amdgcn_sched_barrier(0); \
    __builtin_amdgcn_s_barrier(); \
    __builtin_amdgcn_sched_barrier(0); \
} while (0)

#define VMW0() do { \
    __builtin_amdgcn_sched_barrier(0); \
    asm volatile("s_waitcnt vmcnt(0)" ::: "memory"); \
    __builtin_amdgcn_sched_barrier(0); \
} while (0)

// ---------------------------------------------------------------------------
// Merged prep: blocks [0,6144) cast x fp32->bf16; blocks [6144,8448) build
// Wt[n][k] = bf16(W[k][n]) for the 4 weight matrices. (wtq/wtk/wtv are
// CONTIGUOUS in the workspace -> merged [2304][768] B matrix.)
// ---------------------------------------------------------------------------
__global__ __launch_bounds__(256) void prep_kernel(
    const float* __restrict__ x,
    const float* __restrict__ Wq, const float* __restrict__ Wk,
    const float* __restrict__ Wv, const float* __restrict__ Wo,
    unsigned short* __restrict__ xb,
    unsigned short* __restrict__ tq, unsigned short* __restrict__ tk,
    unsigned short* __restrict__ tv, unsigned short* __restrict__ to_)
{
    __shared__ float tile[32][33];
    const int bid = blockIdx.x;
    const int tid = threadIdx.x;

    if (bid < 6144) {
        int i = (bid * 256 + tid) * 4;
        const float4 v = *(const float4*)(x + i);
        unsigned long long pack =
              (unsigned long long)f2bf(v.x)
            | ((unsigned long long)f2bf(v.y) << 16)
            | ((unsigned long long)f2bf(v.z) << 32)
            | ((unsigned long long)f2bf(v.w) << 48);
        *(unsigned long long*)(xb + i) = pack;
        return;
    }

    const int t   = bid - 6144;       // 0..2303
    const int zz  = t / 576;
    const int rem = t % 576;
    const float* W = (zz == 0) ? Wq : (zz == 1) ? Wk : (zz == 2) ? Wv : Wo;
    unsigned short* T = (zz == 0) ? tq : (zz == 1) ? tk : (zz == 2) ? tv : to_;

    const int bx = (rem / 24) * 32;   // k base
    const int by = (rem % 24) * 32;   // n base
    const int tx = tid & 31, ty = tid >> 5;   // ty 0..7

    #pragma unroll
    for (int i = 0; i < 32; i += 8)
        tile[ty + i][tx] = W[(size_t)(bx + ty + i) * DMODEL + by + tx];
    __syncthreads();
    #pragma unroll
    for (int i = 0; i < 32; i += 8)
        T[(size_t)(by + ty + i) * DMODEL + bx + tx] = f2bf(tile[tx][ty + i]);
}

// ---------------------------------------------------------------------------
// qkv GEMM (UNCHANGED from R5, best measured 45.0us): BM=256 x BN=288, BK=64,
// double-buffered, 256 blocks = 1/CU, XOR chunk swizzle (0 conflicts), one
// barrier + one vmcnt(0) per K-tile.
// ---------------------------------------------------------------------------
#define QSTAGE(kt, sb) do { \
    const int _k0 = (kt) * 64; \
    _Pragma("unroll") \
    for (int _i = 0; _i < 4; ++_i) \
        async_copy16(aSrc + (size_t)_i * (8 * DMODEL) + _k0, &As[sb][(w * 4 + _i) * 512]); \
    _Pragma("unroll") \
    for (int _i = 0; _i < 4; ++_i) \
        async_copy16(bSrc + (size_t)_i * (64 * DMODEL) + _k0, &Bs[sb][(w + 8 * _i) * 512]); \
    if (w < 4) \
        async_copy16(bSrc + (size_t)4 * (64 * DMODEL) + _k0, &Bs[sb][(w + 32) * 512]); \
} while (0)

#define QTILE(t, c, o, hasNext) do { \
    if (hasNext) QSTAGE((t) + 1, o); \
    bf16x8 aF[4][2]; \
    _Pragma("unroll") \
    for (int _m = 0; _m < 4; ++_m) { \
        const int _row = wm * 64 + _m * 16 + l16; \
        aF[_m][0] = *(const bf16x8*)&As[c][_row * 64 + p0]; \
        aF[_m][1] = *(const bf16x8*)&As[c][_row * 64 + (p0 ^ 32)]; \
    } \
    _Pragma("unroll") \
    for (int _nh = 0; _nh < 3; ++_nh) { \
        bf16x8 bF[3][2]; \
        _Pragma("unroll") \
        for (int _n = 0; _n < 3; ++_n) { \
            const int _row = wn * 144 + (_nh * 3 + _n) * 16 + l16; \
            bF[_n][0] = *(const bf16x8*)&Bs[c][_row * 64 + p0]; \
            bF[_n][1] = *(const bf16x8*)&Bs[c][_row * 64 + (p0 ^ 32)]; \
        } \
        __builtin_amdgcn_s_setprio(1); \
        _Pragma("unroll") \
        for (int _k = 0; _k < 2; ++_k) \
          _Pragma("unroll") \
          for (int _m = 0; _m < 4; ++_m) \
            _Pragma("unroll") \
            for (int _n = 0; _n < 3; ++_n) \
              acc[_m][_nh * 3 + _n] = __builtin_amdgcn_mfma_f32_16x16x32_bf16( \
                  aF[_m][_k], bF[_n][_k], acc[_m][_nh * 3 + _n], 0, 0, 0); \
        __builtin_amdgcn_s_setprio(0); \
    } \
    if (hasNext) VMW0(); \
    SBAR(); \
} while (0)

__global__ __launch_bounds__(512, 2) void gemm_db_qkv(
    const unsigned short* __restrict__ xb, const unsigned short* __restrict__ wt,
    const float* __restrict__ bq, const float* __restrict__ bk, const float* __restrict__ bv,
    unsigned short* __restrict__ o0, unsigned short* __restrict__ o1,
    unsigned short* __restrict__ o2)
{
    __shared__ __align__(16) unsigned short As[2][256 * 64];
    __shared__ __align__(16) unsigned short Bs[2][288 * 64];

    // bijective XCD swizzle: 256 blocks = 8 XCDs x 32 contiguous tiles
    const int orig = blockIdx.x;
    const int wg   = (orig & 7) * 32 + (orig >> 3);
    const int m0   = (wg >> 3) * 256;     // 32 M-tiles
    const int n0   = (wg & 7) * 288;      // 8 N-tiles

    const int tid  = threadIdx.x;
    const int lane = tid & 63;
    const int w    = tid >> 6;            // 0..7
    const int wm   = w >> 1, wn = w & 1;  // 4M x 2N wave grid
    const int quad = lane >> 4;
    const int l16  = lane & 15;
    const int rloc = lane >> 3;           // staging: row-within-inst 0..7
    const int csw  = (lane & 7) ^ rloc;   // swizzled logical chunk
    const int p0   = (quad ^ (l16 & 7)) * 8;

    const unsigned short* aSrc = xb + (size_t)(m0 + w * 32 + rloc) * DMODEL + csw * 8;
    const unsigned short* bSrc = wt + (size_t)(n0 + w * 8  + rloc) * DMODEL + csw * 8;

    f32x4 acc[4][9] = {};

    QSTAGE(0, 0);
    VMW0();
    SBAR();

    #pragma unroll 1
    for (int tt = 0; tt < NKT / 2; ++tt) {
        QTILE(2 * tt,     0, 1, 1);
        QTILE(2 * tt + 1, 1, 0, (tt < NKT / 2 - 1));
    }

    // epilogue: per 16-col group, pick q/k/v (wave-uniform: 16 | 768)
    #pragma unroll
    for (int nf = 0; nf < 9; ++nf) {
        const int ncg = n0 + wn * 144 + nf * 16 + l16;
        const int zz  = (ncg >= 1536) ? 2 : (ncg >= 768) ? 1 : 0;
        const int ncl = ncg - zz * 768;
        const int h = ncl >> 6, dh = ncl & 63;
        const float bval = ((zz == 0) ? bq : (zz == 1) ? bk : bv)[ncl];
        if (zz == 2) {
            // V^T layout: [B,H,DH,SEQ], pack 4 consecutive tokens per store
            #pragma unroll
            for (int mi = 0; mi < 4; ++mi) {
                const int mbase = m0 + wm * 64 + mi * 16 + quad * 4;
                const int bi = mbase >> 9, l = mbase & 511;
                unsigned long long pack = 0;
                #pragma unroll
                for (int r = 0; r < 4; ++r)
                    pack |= (unsigned long long)f2bf(acc[mi][nf][r] + bval) << (16 * r);
                *(unsigned long long*)(o2 + ((size_t)((bi * NH + h) * DHEAD + dh)) * SEQ + l) = pack;
            }
        } else {
            // Q/K layout: [B,H,SEQ,DH]; q pre-scaled by ATTN_SCALE
            const float sc = (zz == 0) ? ATTN_SCALE : 1.0f;
            unsigned short* out = (zz == 0) ? o0 : o1;
            #pragma unroll
            for (int mi = 0; mi < 4; ++mi) {
                const int mbase = m0 + wm * 64 + mi * 16 + quad * 4;
                #pragma unroll
                for (int r = 0; r < 4; ++r) {
                    const int t = mbase + r;
                    const int bi = t >> 9, l = t & 511;
                    out[(size_t)((bi * NH + h) * SEQ + l) * DHEAD + dh] =
                        f2bf((acc[mi][nf][r] + bval) * sc);
                }
            }
        }
    }
}

// ---------------------------------------------------------------------------
// O-proj (UNCHANGED from R5): BM=128 x BN=192, 256 blocks = 1/CU, one barrier
// + one vmcnt per tile. Epilogue: y = acc + bo + x.
// ---------------------------------------------------------------------------
#define OSTAGE(kt, sb) do { \
    const int _k0 = (kt) * 64; \
    _Pragma("unroll") \
    for (int _i = 0; _i < 2; ++_i) \
        async_copy16(aSrc + (size_t)_i * (8 * DMODEL) + _k0, &Ao[sb][(w * 2 + _i) * 512]); \
    _Pragma("unroll") \
    for (int _i = 0; _i < 3; ++_i) \
        async_copy16(bSrc + (size_t)_i * (8 * DMODEL) + _k0, &Bo[sb][(w * 3 + _i) * 512]); \
} while (0)

#define OTILE(t, c, o, hasNext) do { \
    if (hasNext) OSTAGE((t) + 1, o); \
    bf16x8 aF[4][2], bF[3][2]; \
    _Pragma("unroll") \
    for (int _m = 0; _m < 4; ++_m) { \
        const int _row = wm * 64 + _m * 16 + l16; \
        aF[_m][0] = *(const bf16x8*)&Ao[c][_row * 64 + p0]; \
        aF[_m][1] = *(const bf16x8*)&Ao[c][_row * 64 + (p0 ^ 32)]; \
    } \
    _Pragma("unroll") \
    for (int _n = 0; _n < 3; ++_n) { \
        const int _row = wn * 48 + _n * 16 + l16; \
        bF[_n][0] = *(const bf16x8*)&Bo[c][_row * 64 + p0]; \
        bF[_n][1] = *(const bf16x8*)&Bo[c][_row * 64 + (p0 ^ 32)]; \
    } \
    __builtin_amdgcn_s_setprio(1); \
    _Pragma("unroll") \
    for (int _k = 0; _k < 2; ++_k) \
      _Pragma("unroll") \
      for (int _m = 0; _m < 4; ++_m) \
        _Pragma("unroll") \
        for (int _n = 0; _n < 3; ++_n) \
          acc[_m][_n] = __builtin_amdgcn_mfma_f32_16x16x32_bf16( \
              aF[_m][_k], bF[_n][_k], acc[_m][_n], 0, 0, 0); \
    __builtin_amdgcn_s_setprio(0); \
    if (hasNext) VMW0(); \
    SBAR(); \
} while (0)

__global__ __launch_bounds__(512, 2) void gemm_db_oproj(
    const unsigned short* __restrict__ ctxb, const unsigned short* __restrict__ wto,
    const float* __restrict__ bo, const float* __restrict__ x,
    float* __restrict__ y)
{
    __shared__ __align__(16) unsigned short Ao[2][132 * 64];   // 128 rows + pad
    __shared__ __align__(16) unsigned short Bo[2][192 * 64];

    const int orig = blockIdx.x;
    const int wg   = (orig & 7) * 32 + (orig >> 3);   // 256 = 8 XCDs x 32
    const int m0   = (wg >> 2) * 128;                 // 64 M-tiles
    const int n0   = (wg & 3) * 192;                  // 4 N-tiles

    const int tid  = threadIdx.x;
    const int lane = tid & 63;
    const int w    = tid >> 6;            // 0..7
    const int wm   = w >> 2, wn = w & 3;  // 2M x 4N wave grid
    const int quad = lane >> 4;
    const int l16  = lane & 15;
    const int rloc = lane >> 3;
    const int csw  = (lane & 7) ^ rloc;
    const int p0   = (quad ^ (l16 & 7)) * 8;

    const unsigned short* aSrc = ctxb + (size_t)(m0 + w * 16 + rloc) * DMODEL + csw * 8;
    const unsigned short* bSrc = wto  + (size_t)(n0 + w * 24 + rloc) * DMODEL + csw * 8;

    f32x4 acc[4][3] = {};

    OSTAGE(0, 0);
    VMW0();
    SBAR();

    #pragma unroll 1
    for (int tt = 0; tt < NKT / 2; ++tt) {
        OTILE(2 * tt,     0, 1, 1);
        OTILE(2 * tt + 1, 1, 0, (tt < NKT / 2 - 1));
    }

    #pragma unroll
    for (int ni = 0; ni < 3; ++ni) {
        const int ncol = n0 + wn * 48 + ni * 16 + l16;
        const float bv_ = bo[ncol];
        #pragma unroll
        for (int mi = 0; mi < 4; ++mi) {
            const int mbase = m0 + wm * 64 + mi * 16 + quad * 4;
            #pragma unroll
            for (int r = 0; r < 4; ++r) {
                const size_t idx = (size_t)(mbase + r) * DMODEL + ncol;
                y[idx] = acc[mi][ni][r] + bv_ + x[idx];
            }
        }
    }
}

// ---------------------------------------------------------------------------
// MFMA flash attention v6: R5's proven staged structure (K/V LDS dbuf +
// async prefetch + per-iter __syncthreads -- the latency-hiding engine R6
// wrongly removed; R6's direct-global variant collapsed to VGPR=44,
// MfmaUtil 4.7, 116us) PLUS one structural change: each block now owns a
// 128-row Q-slab (2 q-tiles). Grid 1536 -> 768 = 3 blocks/CU resident
// exactly (52KB x 3 = 156 <= 160KB LDS), single round. K/V staging and
// barriers amortize over 2x the work; K/V LDS fragments are read ONCE per
// iter and feed both q-tiles. Q loads direct global->regs (read-once; the
// part of R6 that was fine). Mask via LDS table, always-added (exp(s+0)
// bit-identical). XCD locality is natural: the 4 q-slabs of one (b,h) are
// 192 apart in blockIdx, 192 % 8 == 0 -> same XCD L2.
// ---------------------------------------------------------------------------
__global__ __launch_bounds__(256, 3) void attn_mfma_kernel(
    const unsigned short* __restrict__ q, const unsigned short* __restrict__ k,
    const unsigned short* __restrict__ vt, const int* __restrict__ mask,
    unsigned short* __restrict__ ctxb)
{
    __shared__ __align__(16) unsigned short Ks[2][64 * 64];
    __shared__ __align__(16) unsigned short Vs[2][64 * 64];   // V^T: [d][key]
    __shared__ __align__(16) unsigned short Ps[2][64 * PADP];
    __shared__ float maskV[SEQ];

    const int tid  = threadIdx.x;
    const int lane = tid & 63;
    const int w    = tid >> 6;
    const int quad = lane >> 4;
    const int l16  = lane & 15;

    const int id = blockIdx.x;
    const int qt = id / (BATCH * NH);     // 0..3 (128-row q-slab)
    const int g  = id % (BATCH * NH);
    const int b  = g / NH, h = g % NH;
    const int q0 = qt * 128;

    const unsigned short* qp  = q  + ((size_t)(b * NH + h) * SEQ + q0) * DHEAD;
    const unsigned short* kp  = k  + (size_t)(b * NH + h) * SEQ * DHEAD;
    const unsigned short* vtp = vt + (size_t)(b * NH + h) * DHEAD * SEQ;

    const int rloc = lane >> 3;
    const int csw  = (lane & 7) ^ rloc;
    const int p0   = (quad ^ (l16 & 7)) * 8;

    // prologue: stage K/V tile 0; build mask table; Q direct to regs
    #pragma unroll
    for (int ii = 0; ii < 2; ++ii) {
        const int inst = 2 * w + ii;
        async_copy16(kp  + (size_t)(inst * 8 + rloc) * DHEAD + csw * 8, &Ks[0][inst * 512]);
        async_copy16(vtp + (size_t)(inst * 8 + rloc) * SEQ + csw * 8,   &Vs[0][inst * 512]);
    }
    #pragma unroll
    for (int j = 0; j < 2; ++j) {
        const int idx = tid + 256 * j;
        maskV[idx] = (mask[b * SEQ + idx] > 0) ? 0.f : -1e9f;
    }

    bf16x8 aQ[2][2];   // [q-tile][ks]: row = qtl*64 + w*16 + l16, d = ks*32 + quad*8
    #pragma unroll
    for (int qtl = 0; qtl < 2; ++qtl)
        #pragma unroll
        for (int ks = 0; ks < 2; ++ks)
            aQ[qtl][ks] = *(const bf16x8*)(qp + (size_t)(qtl * 64 + w * 16 + l16) * DHEAD
                                              + ks * 32 + quad * 8);

    bf16x8 ones;
    #pragma unroll
    for (int j = 0; j < 8; ++j) ones[j] = (short)0x3F80;   // bf16 1.0

    f32x4 o[2][4] = {};
    f32x4 lsum[2] = {};
    const f32x4 zf = {0.f, 0.f, 0.f, 0.f};

    __syncthreads();   // K/V tile0 landed (vmcnt drain), mask table ready

    #pragma unroll
    for (int it = 0; it < 8; ++it) {
        const int cur = it & 1;
        if (it + 1 < 8) {      // prefetch next K/V tile into the other buffer
            const int kt1 = (it + 1) * 64;
            #pragma unroll
            for (int ii = 0; ii < 2; ++ii) {
                const int inst = 2 * w + ii;
                async_copy16(kp  + (size_t)(kt1 + inst * 8 + rloc) * DHEAD + csw * 8,
                             &Ks[1 - cur][inst * 512]);
                async_copy16(vtp + (size_t)(inst * 8 + rloc) * SEQ + kt1 + csw * 8,
                             &Vs[1 - cur][inst * 512]);
            }
        }
        const int kt = it * 64;

        // S = (Q*scale)·K^T for both q-tiles; K frags read ONCE, used twice
        f32x4 s[2][4];
        #pragma unroll
        for (int ni = 0; ni < 4; ++ni) {
            bf16x8 bK0 = *(const bf16x8*)&Ks[cur][(ni * 16 + l16) * 64 + p0];
            bf16x8 bK1 = *(const bf16x8*)&Ks[cur][(ni * 16 + l16) * 64 + (p0 ^ 32)];
            #pragma unroll
            for (int qtl = 0; qtl < 2; ++qtl) {
                f32x4 t0 = __builtin_amdgcn_mfma_f32_16x16x32_bf16(aQ[qtl][0], bK0, zf, 0, 0, 0);
                s[qtl][ni] = __builtin_amdgcn_mfma_f32_16x16x32_bf16(aQ[qtl][1], bK1, t0, 0, 0, 0);
            }
        }

        // P = exp(S + mask) -> wave-private Ps (truncating bf16 cast)
        #pragma unroll
        for (int ni = 0; ni < 4; ++ni) {
            const float mk = maskV[kt + ni * 16 + l16];
            #pragma unroll
            for (int qtl = 0; qtl < 2; ++qtl)
                #pragma unroll
                for (int r = 0; r < 4; ++r)
                    Ps[qtl][(w * 16 + quad * 4 + r) * PADP + ni * 16 + l16]
                        = (unsigned short)(__float_as_uint(__expf(s[qtl][ni][r] + mk)) >> 16);
        }

        // P back as A-frags (wave-internal round trip; ordered by lgkmcnt)
        bf16x8 aP[2][2];
        #pragma unroll
        for (int qtl = 0; qtl < 2; ++qtl) {
            #pragma unroll
            for (int ks = 0; ks < 2; ++ks)
                aP[qtl][ks] = *(const bf16x8*)&Ps[qtl][(w * 16 + l16) * PADP + quad * 8 + ks * 32];
            lsum[qtl] = __builtin_amdgcn_mfma_f32_16x16x32_bf16(aP[qtl][0], ones, lsum[qtl], 0, 0, 0);
            lsum[qtl] = __builtin_amdgcn_mfma_f32_16x16x32_bf16(aP[qtl][1], ones, lsum[qtl], 0, 0, 0);
        }

        // O += P · V ; V frags read ONCE, used twice
        #pragma unroll
        for (int ni = 0; ni < 4; ++ni) {
            bf16x8 bV0 = *(const bf16x8*)&Vs[cur][(ni * 16 + l16) * 64 + p0];
            bf16x8 bV1 = *(const bf16x8*)&Vs[cur][(ni * 16 + l16) * 64 + (p0 ^ 32)];
            #pragma unroll
            for (int qtl = 0; qtl < 2; ++qtl) {
                o[qtl][ni] = __builtin_amdgcn_mfma_f32_16x16x32_bf16(aP[qtl][0], bV0, o[qtl][ni], 0, 0, 0);
                o[qtl][ni] = __builtin_amdgcn_mfma_f32_16x16x32_bf16(aP[qtl][1], bV1, o[qtl][ni], 0, 0, 0);
            }
        }

        __syncthreads();   // all waves done with buf[cur]; prefetch drained
    }

    // epilogue: ctx[b, tok, h*64 + d] = O / l  (both q-tiles)
    #pragma unroll
    for (int qtl = 0; qtl < 2; ++qtl)
        #pragma unroll
        for (int r = 0; r < 4; ++r) {
            const float inv = 1.f / lsum[qtl][r];
            const int tok = q0 + qtl * 64 + w * 16 + quad * 4 + r;
            #pragma unroll
            for (int ni = 0; ni < 4; ++ni)
                ctxb[(size_t)(b * SEQ + tok) * DMODEL + h * DHEAD + ni * 16 + l16]
                    = f2bf(o[qtl][ni][r] * inv);
        }
}

// ---------------------------------------------------------------------------
// LayerNorm, in-place capable.
// ---------------------------------------------------------------------------
__global__ __launch_bounds__(256) void ln_kernel(
    const float* __restrict__ y, const float* __restrict__ gamma,
    const float* __restrict__ beta, float* __restrict__ out)
{
    const int t   = blockIdx.x;
    const int tid = threadIdx.x;
    const float* row = y + (size_t)t * DMODEL;

    float vals[3];
    float s = 0.f, s2 = 0.f;
    #pragma unroll
    for (int i = 0; i < 3; ++i) {
        float vv = row[tid + 256 * i];
        vals[i] = vv;
        s  += vv;
        s2 += vv * vv;
    }
    #pragma unroll
    for (int off = 32; off > 0; off >>= 1) {
        s  += __shfl_down(s,  off);
        s2 += __shfl_down(s2, off);
    }
    __shared__ float rbuf[8];
    int w = tid >> 6;
    if ((tid & 63) == 0) { rbuf[w] = s; rbuf[4 + w] = s2; }
    __syncthreads();
    float ts  = rbuf[0] + rbuf[1] + rbuf[2] + rbuf[3];
    float ts2 = rbuf[4] + rbuf[5] + rbuf[6] + rbuf[7];
    float mu  = ts * (1.f / DMODEL);
    float var = ts2 * (1.f / DMODEL) - mu * mu;
    float inv = rsqrtf(var + LN_EPS);
    #pragma unroll
    for (int i = 0; i < 3; ++i) {
        int c = tid + 256 * i;
        out[(size_t)t * DMODEL + c] = gamma[c] * (vals[i] - mu) * inv + beta[c];
    }
}

// ---------------------------------------------------------------------------
extern "C" void kernel_launch(void* const* d_in, const int* in_sizes, int n_in,
                              void* d_out, int out_size, void* d_ws, size_t ws_size,
                              hipStream_t stream) {
    const float* x     = (const float*)d_in[0];
    const int*   mask  = (const int*)  d_in[1];
    const float* Wq    = (const float*)d_in[2];
    const float* bq    = (const float*)d_in[3];
    const float* Wk    = (const float*)d_in[4];
    const float* bk    = (const float*)d_in[5];
    const float* Wv    = (const float*)d_in[6];
    const float* bv    = (const float*)d_in[7];
    const float* Wo    = (const float*)d_in[8];
    const float* bo    = (const float*)d_in[9];
    const float* gamma = (const float*)d_in[10];
    const float* beta  = (const float*)d_in[11];
    float* out = (float*)d_out;

    const size_t perTok = (size_t)NTOK * DMODEL;   // 6,291,456
    const size_t perW   = (size_t)DMODEL * DMODEL; //   589,824

    unsigned short* xb   = (unsigned short*)d_ws;
    unsigned short* wtq  = xb + perTok;            // wtq/wtk/wtv contiguous:
    unsigned short* wtk  = wtq + perW;             //   merged B = [2304][768]
    unsigned short* wtv  = wtk + perW;
    unsigned short* wto  = wtv + perW;
    unsigned short* qb   = wto + perW;
    unsigned short* kb   = qb + perTok;
    unsigned short* vb   = kb + perTok;            // holds V^T: [B,H,DH,SEQ]
    unsigned short* ctxb = vb + perTok;
    float* y = out;   // O-proj output lives in d_out; LN runs in-place

    prep_kernel<<<6144 + 2304, 256, 0, stream>>>(
        x, Wq, Wk, Wv, Wo, xb, wtq, wtk, wtv, wto);

    // merged QKV GEMM: [8192 x 768] x [768 x 2304], 256 blocks = 1/CU exact
    gemm_db_qkv<<<256, 512, 0, stream>>>(xb, wtq, bq, bk, bv, qb, kb, vb);

    // attention: 128-row q-slabs, 768 blocks = 3/CU resident exactly
    attn_mfma_kernel<<<dim3((SEQ / 128) * BATCH * NH), 256, 0, stream>>>(
        qb, kb, vb, mask, ctxb);

    // O-proj: [8192 x 768] x [768 x 768], 256 blocks = 1/CU exact
    gemm_db_oproj<<<256, 512, 0, stream>>>(ctxb, wto, bo, x, y);

    ln_kernel<<<NTOK, 256, 0, stream>>>(y, gamma, beta, out);
}